// Round 5
// baseline (563.369 us; speedup 1.0000x reference)
//
#include <hip/hip_runtime.h>
#include <math.h>

#define N_TOK 8192
#define DIM   1024
#define HID   2048
#define NE    8
#define NPAIR (N_TOK * 2)          // 16384 (token, expert) pairs exactly
#define CAPP  (NPAIR + NE * 128)   // 17408: expert regions padded to 128 rows
#define TAIL  (N_TOK * DIM)        // offset of scalar outputs in d_out

typedef __bf16 bf16x8_t __attribute__((ext_vector_type(8)));
typedef float  f32x4_t  __attribute__((ext_vector_type(4)));

__device__ __forceinline__ unsigned short f2bf(float f) {
  union { float f; unsigned u; } v; v.f = f;
  unsigned r = v.u + 0x7fffu + ((v.u >> 16) & 1u);   // RNE
  return (unsigned short)(r >> 16);
}

__device__ __forceinline__ float bf2f(unsigned short h) {
  union { unsigned u; float f; } v; v.u = ((unsigned)h) << 16;
  return v.f;
}

// exact-equivalent GELU: A&S 7.1.26 erf approx, |eps|<=1.5e-7 (~15 instr vs ~50 for libm erff)
__device__ __forceinline__ float gelu_fast(float v) {
  float u = v * 0.70710678118654752440f;
  float z = fabsf(u);
  float t = 1.f / (1.f + 0.3275911f * z);
  float poly = t * (0.254829592f + t * (-0.284496736f + t * (1.421413741f +
               t * (-1.453152027f + t * 1.061405429f))));
  float er = 1.f - poly * __expf(-z * z);
  er = (u < 0.f) ? -er : er;
  return 0.5f * v * (1.f + er);
}

// async global->LDS DMA, 16B/lane; LDS base wave-uniform, HW scatters lane*16.
__device__ __forceinline__ void load16_lds(const void* g, void* l) {
  __builtin_amdgcn_global_load_lds(
      (const __attribute__((address_space(1))) unsigned int*)g,
      (__attribute__((address_space(3))) unsigned int*)l, 16, 0, 0);
}

// =======================================================================
// Fragment-chunk global layout (R4, kept): matrix [R rows][Kd k] as 1KB
// chunks; chunk c = (r>>4)*(Kd/32) + (k>>5); within a chunk lane
// l = ((k>>3)&3)*16 + (r&15) owns 16B (k&7 fastest). One contiguous-1KB
// global_load_lds per chunk; ds_read_b128 sequential (0 conflicts).
// R5: persistent GEMMs (1024 blocks = 4/CU pop tiles from a work queue),
// gemm1 epilogue LDS-repack -> 8x16B coalesced He stores, fast GELU.
// =======================================================================

// ---------------- weights fp32 [z][Kd][R] -> frag-chunk bf16 ----------------
template<int KD, int RR>
__global__ __launch_bounds__(256) void w_to_frag(const float* __restrict__ src,
                                                 unsigned short* __restrict__ dst) {
  constexpr int KD32 = KD / 32;
  int z = blockIdx.z;
  int cl = blockIdx.x * 4 + (threadIdx.x >> 6);   // chunk id (grid sized exactly)
  int lane = threadIdx.x & 63, m16 = lane & 15, q = lane >> 4;
  int rblk = cl / KD32, kblk = cl % KD32;         // pow2 -> shifts
  int r = rblk * 16 + m16;
  int kb = kblk * 32 + q * 8;
  const float* s = src + (size_t)z * KD * RR + (size_t)kb * RR + r;
  unsigned short t[8];
  #pragma unroll
  for (int j = 0; j < 8; ++j) t[j] = f2bf(s[(size_t)j * RR]);
  *(uint4*)(dst + (size_t)z * KD * RR + (size_t)cl * 512 + lane * 8) = *(uint4*)t;
}

// ---------------- router: logits (fp32), top-2, softmax, aux stats ----------------
#define R_BLOCKS 512
#define R_TPW    (N_TOK / (R_BLOCKS * 4))   // 4 tokens per wave
__global__ __launch_bounds__(256) void router_kernel(
    const float* __restrict__ x, const float* __restrict__ gW, const float* __restrict__ gb,
    int* __restrict__ tok_e, float* __restrict__ tok_g,
    int* __restrict__ cnt, float* __restrict__ imp, float* __restrict__ ent_sum) {
  __shared__ int s_cnt[NE];
  __shared__ float s_imp[NE];
  __shared__ float s_ent;
  int tid = threadIdx.x;
  if (tid < NE) { s_cnt[tid] = 0; s_imp[tid] = 0.f; }
  if (tid == 0) s_ent = 0.f;
  __syncthreads();
  int wid = tid >> 6, lane = tid & 63;
  int t0 = (blockIdx.x * 4 + wid) * R_TPW;
  float imp_loc[8] = {0.f, 0.f, 0.f, 0.f, 0.f, 0.f, 0.f, 0.f};
  float ent_loc = 0.f;
  for (int t = 0; t < R_TPW; ++t) {
    int n = t0 + t;
    const float* xr = x + (size_t)n * DIM;
    float p[8] = {0.f, 0.f, 0.f, 0.f, 0.f, 0.f, 0.f, 0.f};
    #pragma unroll
    for (int it = 0; it < DIM / 64; ++it) {
      int d = lane + (it << 6);
      float xv = xr[d];
      const float4* g4 = (const float4*)(gW + (size_t)d * NE);
      float4 a = g4[0], b = g4[1];
      p[0] += xv * a.x; p[1] += xv * a.y; p[2] += xv * a.z; p[3] += xv * a.w;
      p[4] += xv * b.x; p[5] += xv * b.y; p[6] += xv * b.z; p[7] += xv * b.w;
    }
    #pragma unroll
    for (int e = 0; e < 8; ++e)
      for (int o = 32; o > 0; o >>= 1) p[e] += __shfl_down(p[e], o, 64);
    if (lane == 0) {
      float lg[8];
      #pragma unroll
      for (int e = 0; e < 8; ++e) lg[e] = p[e] + gb[e];
      int i0 = 0;
      #pragma unroll
      for (int e = 1; e < 8; ++e) if (lg[e] > lg[i0]) i0 = e;   // ties -> lowest idx
      int i1 = (i0 == 0) ? 1 : 0;
      #pragma unroll
      for (int e = 0; e < 8; ++e) if (e != i0 && lg[e] > lg[i1]) i1 = e;
      float d1 = expf(lg[i1] - lg[i0]);
      float g0 = 1.f / (1.f + d1);
      float g1 = d1 * g0;
      tok_e[2 * n] = i0; tok_e[2 * n + 1] = i1;
      tok_g[2 * n] = g0; tok_g[2 * n + 1] = g1;
      atomicAdd(&s_cnt[i0], 1);
      atomicAdd(&s_cnt[i1], 1);
      float mx = lg[i0], s = 0.f, pe[8];
      #pragma unroll
      for (int e = 0; e < 8; ++e) { pe[e] = expf(lg[e] - mx); s += pe[e]; }
      float inv = 1.f / s;
      #pragma unroll
      for (int e = 0; e < 8; ++e) {
        float pr = pe[e] * inv;
        imp_loc[e] += pr;
        ent_loc -= pr * logf(pr + 1e-8f);
      }
    }
  }
  if (lane == 0) {
    #pragma unroll
    for (int e = 0; e < 8; ++e) atomicAdd(&s_imp[e], imp_loc[e]);
    atomicAdd(&s_ent, ent_loc);
  }
  __syncthreads();
  const float invN = 1.f / (float)N_TOK;
  if (tid < NE) {
    atomicAdd(&cnt[tid], s_cnt[tid]);
    atomicAdd(&imp[tid], s_imp[tid] * invN);
  }
  if (tid == NE) atomicAdd(ent_sum, s_ent * invN);
}

// ---------------- finalize: padded offsets, tile tables, scalar outputs ----------------
__global__ void finalize_kernel(const int* __restrict__ cnt, int* __restrict__ poffs,
                                int* __restrict__ cursor, int* __restrict__ tb1,
                                int* __restrict__ tb2, const float* __restrict__ imp,
                                const float* __restrict__ ent_sum, float* __restrict__ out_tail) {
  if (threadIdx.x == 0) {
    int off = 0, t1 = 0, t2 = 0; float bal = 0.f, util = 0.f;
    for (int e = 0; e < NE; ++e) {
      poffs[e] = off; cursor[e] = off; tb1[e] = t1; tb2[e] = t2;
      int pc = ((cnt[e] + 127) >> 7) << 7;   // 128-aligned region per expert
      off += pc;
      int nt = pc >> 7;                      // 128-row tiles
      t1 += nt * (HID / 128);                // gemm1: 16 col-tiles
      t2 += nt * (DIM / 128);                // gemm2: 8 col-tiles
      float ld = (float)cnt[e] * (1.f / (float)N_TOK);
      float im = imp[e];
      out_tail[3 + e] = ld;        // load
      out_tail[11 + e] = im;       // importance
      bal += im * ld;
      util -= ld * logf(ld + 1e-8f);
    }
    poffs[NE] = off; tb1[NE] = t1; tb2[NE] = t2;
    out_tail[0] = (float)NE * bal; // balance_loss
    out_tail[1] = *ent_sum;        // entropy
    out_tail[2] = util;            // utilization_entropy
  }
}

// ---------------- scatter pairs into (padded) expert buckets ----------------
__global__ __launch_bounds__(256) void scatter_kernel(
    const int* __restrict__ tok_e, const float* __restrict__ tok_g,
    int* __restrict__ cursor, int* __restrict__ row_token, float* __restrict__ row_gate,
    int* __restrict__ pair_slot) {
  __shared__ int s_cnt[NE], s_base[NE], s_rank[NE];
  int tid = threadIdx.x;
  if (tid < NE) { s_cnt[tid] = 0; s_rank[tid] = 0; }
  __syncthreads();
  int n = blockIdx.x * 256 + tid;
  int e0 = tok_e[2 * n], e1 = tok_e[2 * n + 1];
  atomicAdd(&s_cnt[e0], 1);
  atomicAdd(&s_cnt[e1], 1);
  __syncthreads();
  if (tid < NE) s_base[tid] = atomicAdd(&cursor[tid], s_cnt[tid]);
  __syncthreads();
  int r0 = atomicAdd(&s_rank[e0], 1);
  int s0 = s_base[e0] + r0;
  row_token[s0] = n; row_gate[s0] = tok_g[2 * n]; pair_slot[2 * n] = s0;
  int r1 = atomicAdd(&s_rank[e1], 1);
  int s1 = s_base[e1] + r1;
  row_token[s1] = n; row_gate[s1] = tok_g[2 * n + 1]; pair_slot[2 * n + 1] = s1;
}

// ---------------- gather bucketed A (x rows -> frag-chunk bf16, Kd=1024) ----------------
__global__ __launch_bounds__(256) void gather_a1(
    const float* __restrict__ x, const int* __restrict__ row_token,
    const int* __restrict__ cnt, const int* __restrict__ poffs,
    unsigned short* __restrict__ Ab1) {
  int e = blockIdx.z;
  int base = poffs[e];
  int pcnt = poffs[e + 1] - base;
  int nch = (pcnt >> 4) * 32;
  int cl = blockIdx.x * 4 + (threadIdx.x >> 6);
  if (cl >= nch) return;
  int lane = threadIdx.x & 63, m16 = lane & 15, q = lane >> 4;
  int rblk = cl >> 5, kblk = cl & 31;
  int sl = rblk * 16 + m16;
  int slot = base + sl;
  int tok = (sl < cnt[e]) ? row_token[slot] : 0;   // pad rows: token 0 (finite)
  int k = kblk * 32 + q * 8;
  const float4* sp = (const float4*)(x + (size_t)tok * DIM + k);
  float4 v0 = sp[0], v1 = sp[1];
  unsigned short t[8] = {f2bf(v0.x), f2bf(v0.y), f2bf(v0.z), f2bf(v0.w),
                         f2bf(v1.x), f2bf(v1.y), f2bf(v1.z), f2bf(v1.w)};
  *(uint4*)(Ab1 + ((size_t)(slot >> 4) * 32 + kblk) * 512 + lane * 8) = *(uint4*)t;
}

// ---------------- GEMM1 (persistent): He = gelu(Ab1 @ W1f + b1), frag out ----------------
__global__ __launch_bounds__(256, 4) void expert_gemm1(
    const unsigned short* __restrict__ Ab1,   // frag, Kd32=32
    const unsigned short* __restrict__ W1f,   // [E] frag, rows=HID, Kd32=32
    const float* __restrict__ b1,             // [E][H]
    const int* __restrict__ poffs, const int* __restrict__ tb1,
    int* __restrict__ wq,
    unsigned short* __restrict__ He) {        // frag, rows=CAPP, Kd32=64
  __shared__ __align__(16) unsigned short Sm[16384];   // 32KB: As | Bs; reused as repack
  __shared__ int s_tb[NE + 1], s_po[NE + 1], s_t;
  int tid = threadIdx.x;
  if (tid <= NE) { s_tb[tid] = tb1[tid]; s_po[tid] = poffs[tid]; }
  int wid = tid >> 6, lane = tid & 63;
  int m16 = lane & 15, q = lane >> 4;
  int wr = (wid & 1) << 6, wc = (wid >> 1) << 6;
  int ra = wr >> 4, rc = wc >> 4;
  unsigned short* As = Sm;
  unsigned short* Bs = Sm + 8192;
  unsigned short* lA = As + wid * 2048;
  unsigned short* lB = Bs + wid * 2048;
  unsigned short* Rg = Sm + wid * 4096;     // 8KB per-wave repack region
  for (;;) {
    if (tid == 0) s_t = atomicAdd(wq, 1);
    __syncthreads();
    int t = s_t;
    if (t >= s_tb[NE]) break;
    int e = 0;
    #pragma unroll
    for (int k = 1; k < NE; ++k) e += (t >= s_tb[k]);
    int lt = t - s_tb[e];
    int rt = lt >> 4, ct = lt & 15;
    int base = s_po[e];
    int row0 = rt * 128, col0 = ct * 128;
    const unsigned short* Ag = Ab1 + ((size_t)(((base + row0) >> 4) + wid * 2) * 32) * 512 + lane * 8;
    const unsigned short* Bg = W1f + (size_t)e * (HID * DIM)
                             + ((size_t)((col0 >> 4) + wid * 2) * 32) * 512 + lane * 8;
    f32x4_t zero4 = {0.f, 0.f, 0.f, 0.f};
    f32x4_t acc[4][4];
    #pragma unroll
    for (int i = 0; i < 4; ++i)
      #pragma unroll
      for (int j = 0; j < 4; ++j) acc[i][j] = zero4;
    for (int k0 = 0; k0 < DIM; k0 += 64) {
      int kc = (k0 >> 5) * 512;
      load16_lds(Ag + kc,                  lA);
      load16_lds(Ag + kc + 512,            lA + 512);
      load16_lds(Ag + kc + 32 * 512,       lA + 1024);
      load16_lds(Ag + kc + 32 * 512 + 512, lA + 1536);
      load16_lds(Bg + kc,                  lB);
      load16_lds(Bg + kc + 512,            lB + 512);
      load16_lds(Bg + kc + 32 * 512,       lB + 1024);
      load16_lds(Bg + kc + 32 * 512 + 512, lB + 1536);
      __syncthreads();
      #pragma unroll
      for (int ks = 0; ks < 2; ++ks) {
        bf16x8_t a[4], b[4];
        #pragma unroll
        for (int i = 0; i < 4; ++i) {
          a[i] = *(const bf16x8_t*)&As[((ra + i) * 2 + ks) * 512 + lane * 8];
          b[i] = *(const bf16x8_t*)&Bs[((rc + i) * 2 + ks) * 512 + lane * 8];
        }
        #pragma unroll
        for (int i = 0; i < 4; ++i)
          #pragma unroll
          for (int j = 0; j < 4; ++j)
            acc[i][j] = __builtin_amdgcn_mfma_f32_16x16x32_bf16(a[i], b[j], acc[i][j], 0, 0, 0);
      }
      __syncthreads();
    }
    // epilogue: bias + gelu -> per-wave LDS region in frag-chunk order (wave-local,
    // no barrier), then 8 coalesced 16B stores (vs 64 scattered 2B stores in R4).
    const float* b1e = b1 + (size_t)e * HID;
    float b1v[4];
    #pragma unroll
    for (int j = 0; j < 4; ++j) b1v[j] = b1e[col0 + wc + j * 16 + m16];
    #pragma unroll
    for (int i = 0; i < 4; ++i)
      #pragma unroll
      for (int j = 0; j < 4; ++j)
        #pragma unroll
        for (int rr = 0; rr < 4; ++rr) {
          float v = acc[i][j][rr] + b1v[j];
          Rg[(i * 2 + (j >> 1)) * 512 +
             (((j & 1) * 2 + (m16 >> 3)) * 16 + q * 4 + rr) * 8 + (m16 & 7)] = f2bf(gelu_fast(v));
        }
    int sb0 = ((base + row0) >> 4) + ra;
    int kg0 = (col0 >> 5) + (wc >> 5);
    #pragma unroll
    for (int c = 0; c < 8; ++c) {
      size_t go = ((size_t)(sb0 + (c >> 1)) * 64 + kg0 + (c & 1)) * 512 + lane * 8;
      *(uint4*)(He + go) = *(uint4*)&Rg[c * 512 + lane * 8];
    }
    __syncthreads();   // LDS free + s_t guard before next tile
  }
}

// ---------------- GEMM2 (persistent): yb[slot] = He @ W2f (row-major out) ----------------
__global__ __launch_bounds__(256, 4) void expert_gemm2(
    const unsigned short* __restrict__ He,    // frag, Kd32=64
    const unsigned short* __restrict__ W2f,   // [E] frag, rows=DIM, Kd32=64
    const int* __restrict__ poffs, const int* __restrict__ tb2,
    int* __restrict__ wq,
    unsigned short* __restrict__ yb) {        // [CAPP][DIM] row-major
  __shared__ __align__(16) unsigned short Sm[16384];
  __shared__ int s_tb[NE + 1], s_po[NE + 1], s_t;
  int tid = threadIdx.x;
  if (tid <= NE) { s_tb[tid] = tb2[tid]; s_po[tid] = poffs[tid]; }
  int wid = tid >> 6, lane = tid & 63;
  int m16 = lane & 15, q = lane >> 4;
  int wr = (wid & 1) << 6, wc = (wid >> 1) << 6;
  int ra = wr >> 4, rc = wc >> 4;
  unsigned short* As = Sm;
  unsigned short* Bs = Sm + 8192;
  unsigned short* lA = As + wid * 2048;
  unsigned short* lB = Bs + wid * 2048;
  for (;;) {
    if (tid == 0) s_t = atomicAdd(wq, 1);
    __syncthreads();
    int t = s_t;
    if (t >= s_tb[NE]) break;
    int e = 0;
    #pragma unroll
    for (int k = 1; k < NE; ++k) e += (t >= s_tb[k]);
    int lt = t - s_tb[e];
    int rt = lt >> 3, ct = lt & 7;
    int base = s_po[e];
    int row0 = rt * 128, col0 = ct * 128;
    const unsigned short* Ag = He + ((size_t)(((base + row0) >> 4) + wid * 2) * 64) * 512 + lane * 8;
    const unsigned short* Bg = W2f + (size_t)e * (DIM * HID)
                             + ((size_t)((col0 >> 4) + wid * 2) * 64) * 512 + lane * 8;
    f32x4_t zero4 = {0.f, 0.f, 0.f, 0.f};
    f32x4_t acc[4][4];
    #pragma unroll
    for (int i = 0; i < 4; ++i)
      #pragma unroll
      for (int j = 0; j < 4; ++j) acc[i][j] = zero4;
    for (int k0 = 0; k0 < HID; k0 += 64) {
      int kc = (k0 >> 5) * 512;
      load16_lds(Ag + kc,                  lA);
      load16_lds(Ag + kc + 512,            lA + 512);
      load16_lds(Ag + kc + 64 * 512,       lA + 1024);
      load16_lds(Ag + kc + 64 * 512 + 512, lA + 1536);
      load16_lds(Bg + kc,                  lB);
      load16_lds(Bg + kc + 512,            lB + 512);
      load16_lds(Bg + kc + 64 * 512,       lB + 1024);
      load16_lds(Bg + kc + 64 * 512 + 512, lB + 1536);
      __syncthreads();
      #pragma unroll
      for (int ks = 0; ks < 2; ++ks) {
        bf16x8_t a[4], b[4];
        #pragma unroll
        for (int i = 0; i < 4; ++i) {
          a[i] = *(const bf16x8_t*)&As[((ra + i) * 2 + ks) * 512 + lane * 8];
          b[i] = *(const bf16x8_t*)&Bs[((rc + i) * 2 + ks) * 512 + lane * 8];
        }
        #pragma unroll
        for (int i = 0; i < 4; ++i)
          #pragma unroll
          for (int j = 0; j < 4; ++j)
            acc[i][j] = __builtin_amdgcn_mfma_f32_16x16x32_bf16(a[i], b[j], acc[i][j], 0, 0, 0);
      }
      __syncthreads();
    }
    #pragma unroll
    for (int i = 0; i < 4; ++i)
      #pragma unroll
      for (int rr = 0; rr < 4; ++rr) {
        size_t slot = (size_t)(base + row0 + wr + i * 16 + q * 4 + rr);
        #pragma unroll
        for (int j = 0; j < 4; ++j) {
          int col = col0 + wc + j * 16 + m16;
          yb[slot * DIM + col] = f2bf(acc[i][j][rr]);
        }
      }
    __syncthreads();
  }
}

// ---------------- gather + gate + bias + residual + LayerNorm ----------------
__global__ __launch_bounds__(256) void ln_kernel(
    const float* __restrict__ x, const unsigned short* __restrict__ yb,
    const int* __restrict__ tok_e, const float* __restrict__ tok_g,
    const int* __restrict__ pair_slot, const float* __restrict__ b2,
    const float* __restrict__ gamma, const float* __restrict__ beta,
    float* __restrict__ out) {
  int n = blockIdx.x, tid = threadIdx.x;
  int e0 = tok_e[2 * n], e1 = tok_e[2 * n + 1];
  float g0 = tok_g[2 * n], g1 = tok_g[2 * n + 1];
  size_t s0 = (size_t)pair_slot[2 * n], s1 = (size_t)pair_slot[2 * n + 1];
  const float* xr = x + (size_t)n * DIM;
  const unsigned short* y0 = yb + s0 * DIM;
  const unsigned short* y1 = yb + s1 * DIM;
  const float* b2e0 = b2 + (size_t)e0 * DIM;
  const float* b2e1 = b2 + (size_t)e1 * DIM;
  float z[4], s = 0.f, s2 = 0.f;
  #pragma unroll
  for (int jj = 0; jj < 4; ++jj) {
    int d = tid + (jj << 8);
    float v = xr[d] + g0 * (bf2f(y0[d]) + b2e0[d]) + g1 * (bf2f(y1[d]) + b2e1[d]);
    z[jj] = v; s += v; s2 += v * v;
  }
  for (int o = 32; o > 0; o >>= 1) { s += __shfl_down(s, o, 64); s2 += __shfl_down(s2, o, 64); }
  __shared__ float rs[4], rs2[4];
  int wid = tid >> 6, lane = tid & 63;
  if (lane == 0) { rs[wid] = s; rs2[wid] = s2; }
  __syncthreads();
  float ts = rs[0] + rs[1] + rs[2] + rs[3];
  float ts2 = rs2[0] + rs2[1] + rs2[2] + rs2[3];
  float mu = ts * (1.f / DIM);
  float var = ts2 * (1.f / DIM) - mu * mu;
  float rstd = rsqrtf(var + 1e-5f);
  float* orow = out + (size_t)n * DIM;
  #pragma unroll
  for (int jj = 0; jj < 4; ++jj) {
    int d = tid + (jj << 8);
    orow[d] = (z[jj] - mu) * rstd * gamma[d] + beta[d];
  }
}

extern "C" void kernel_launch(void* const* d_in, const int* in_sizes, int n_in,
                              void* d_out, int out_size, void* d_ws, size_t ws_size,
                              hipStream_t stream) {
  const float* x     = (const float*)d_in[0];
  const float* gW    = (const float*)d_in[1];
  const float* gb    = (const float*)d_in[2];
  const float* W1    = (const float*)d_in[3];
  const float* b1    = (const float*)d_in[4];
  const float* W2    = (const float*)d_in[5];
  const float* b2    = (const float*)d_in[6];
  const float* gamma = (const float*)d_in[7];
  const float* beta  = (const float*)d_in[8];
  float* out = (float*)d_out;

  // workspace layout (~166 MB), all chunks 16B-aligned
  char* w = (char*)d_ws;
  unsigned short* W1f = (unsigned short*)w; w += (size_t)NE * HID * DIM * 2;
  unsigned short* W2f = (unsigned short*)w; w += (size_t)NE * DIM * HID * 2;
  unsigned short* He  = (unsigned short*)w; w += (size_t)CAPP * HID * 2;
  unsigned short* AbY = (unsigned short*)w; w += (size_t)CAPP * DIM * 2;  // Ab1, then yb (aliased)
  int*   row_token    = (int*)w;            w += (size_t)CAPP * 4;
  float* row_gate     = (float*)w;          w += (size_t)CAPP * 4;
  int*   tok_e        = (int*)w;            w += (size_t)NPAIR * 4;
  float* tok_g        = (float*)w;          w += (size_t)NPAIR * 4;
  int*   pair_slot    = (int*)w;            w += (size_t)NPAIR * 4;
  float* imp          = (float*)w;          // 8 floats
  float* ent_sum      = imp + 8;            // 1 float
  int*   wq1          = (int*)(imp + 9);    // gemm1 work-queue counter
  int*   wq2          = (int*)(imp + 10);   // gemm2 work-queue counter
  int*   cntp         = (int*)(imp + 16);   // 8 ints
  int*   cursor       = cntp + 8;           // 8 ints
  int*   poffs        = cursor + 8;         // 9 ints
  int*   tb1          = poffs + 9;          // 9 ints (gemm1 tile prefix)
  int*   tb2          = tb1 + 9;            // 9 ints (gemm2 tile prefix)

  unsigned short* Ab1 = AbY;                // gemm1 input (dead after gemm1)
  unsigned short* yb  = AbY;                // gemm2 output (written after Ab1 dead)

  hipMemsetAsync(imp, 0, 512, stream);      // imp, ent_sum, wq1/wq2, cnt (+rest rewritten)

  w_to_frag<DIM, HID><<<dim3(1024, 1, NE), 256, 0, stream>>>(W1, W1f);
  w_to_frag<HID, DIM><<<dim3(1024, 1, NE), 256, 0, stream>>>(W2, W2f);
  router_kernel<<<R_BLOCKS, 256, 0, stream>>>(x, gW, gb, tok_e, tok_g, cntp, imp, ent_sum);
  finalize_kernel<<<1, 64, 0, stream>>>(cntp, poffs, cursor, tb1, tb2, imp, ent_sum, out + TAIL);
  scatter_kernel<<<N_TOK / 256, 256, 0, stream>>>(tok_e, tok_g, cursor, row_token, row_gate, pair_slot);
  gather_a1<<<dim3(4096, 1, NE), 256, 0, stream>>>(x, row_token, cntp, poffs, Ab1);
  expert_gemm1<<<1024, 256, 0, stream>>>(Ab1, W1f, b1, poffs, tb1, wq1, He);
  expert_gemm2<<<1024, 256, 0, stream>>>(He, W2f, poffs, tb2, wq2, yb);
  ln_kernel<<<N_TOK, 256, 0, stream>>>(x, yb, tok_e, tok_g, pair_slot, b2, gamma, beta, out);
}